// Round 18
// baseline (1049.847 us; speedup 1.0000x reference)
//
#include <hip/hip_runtime.h>
#include <type_traits>

typedef float f32x2 __attribute__((ext_vector_type(2)));

constexpr int IT_ = 31;
constexpr int FB_ = 15;
constexpr int HID_ = 32;
constexpr int T_LEN = 32768;
constexpr int NSEG = 8;            // parallel time segments per chain
constexpr int WARM = 512;          // warm-up steps (discarded) per segment
// Balanced split: every wave computes exactly SEG0LEN steps.
constexpr int SEGLEN = (T_LEN - WARM) / NSEG;   // 4032
constexpr int SEG0LEN = SEGLEN + WARM;          // 4544
// 2 * log2(e): pre-scales W1/b1 so e^{2*preact} == 2^{acc}  (same as r4..r13)
constexpr float K2LOG2E = 2.8853900817779268f;
constexpr float KS1 = 11.541560327111708f;     // 8*log2(e)
constexpr float KS0 = -5.770780163555854f;     // -4*log2(e)

static_assert(SEG0LEN % 32 == 0 && SEGLEN % 32 == 0 && WARM % 32 == 0, "chunk align");
static_assert(SEG0LEN + (NSEG - 1) * SEGLEN == T_LEN, "coverage");

template<int N, typename F>
__device__ __forceinline__ void static_for(F&& f) {
  if constexpr (N > 0) {
    static_for<N - 1>(f);
    f(std::integral_constant<int, N - 1>{});
  }
}

__device__ __forceinline__ f32x2 make2(float s) { return f32x2{s, s}; }

// packed fma: two independent scalar fmas, identical rounding to v_fma_f32.
__device__ __forceinline__ f32x2 pk_fma(f32x2 a, f32x2 b, f32x2 c) {
  return __builtin_elementwise_fma(a, b, c);
}

// per-half dpp; then one packed add. Order (v + dpp(v)) identical to r4..r13.
template<int CTRL>
__device__ __forceinline__ f32x2 dpp_add2(f32x2 v) {
  f32x2 d;
  d.x = __int_as_float(__builtin_amdgcn_update_dpp(0, __float_as_int(v.x), CTRL, 0xf, 0xf, false));
  d.y = __int_as_float(__builtin_amdgcn_update_dpp(0, __float_as_int(v.y), CTRL, 0xf, 0xf, false));
  return v + d;
}

template<int OFF>
__device__ __forceinline__ float swz(float v) {
  return __int_as_float(__builtin_amdgcn_ds_swizzle(__float_as_int(v), OFF));
}

__device__ __forceinline__ float exp2_raw(float x) {
#if __has_builtin(__builtin_amdgcn_exp2f)
  return __builtin_amdgcn_exp2f(x);
#else
  float r;
  asm("v_exp_f32 %0, %1" : "=v"(r) : "v"(x));
  return r;
#endif
}

// sum of row0+row1 within each 32-lane half, result in ALL lanes.
__device__ __forceinline__ float cross_row16_add(float v) {
#if __has_builtin(__builtin_amdgcn_permlane16_swap)
  typedef int v2i __attribute__((ext_vector_type(2)));
  v2i pr = __builtin_amdgcn_permlane16_swap(__float_as_int(v), __float_as_int(v),
                                            false, false);
  return __int_as_float(pr.x) + __int_as_float(pr.y);
#else
  float u;
  float t = v;
  asm("v_mov_b32 %0, %1\n\t"
      "v_permlane16_swap_b32 %0, %1"
      : "=&v"(u), "+v"(t));
  return u + t;
#endif
}

// r13 kernel exactly (best verified: 1155 us, absmax 0.015625), with ONE
// change: WARM 1024->512 (r16's dual-stream spilled at 256 arch VGPRs and is
// abandoned; r14/r15 stall-fill attempts regressed). Pure -9% work count in
// an issue-bound regime; per-step code byte-identical to r13.
__global__ __launch_bounds__(64)
__attribute__((amdgpu_waves_per_eu(1, 1)))
void wdrnn_eq_kernel(const float* __restrict__ x,
                     const float* __restrict__ W1,
                     const float* __restrict__ b1,
                     const float* __restrict__ W2,
                     const float* __restrict__ b2,
                     float* __restrict__ out) {
  const int lane = threadIdx.x;       // 0..63
  const int j = lane & 31;            // hidden unit index
  const int half = lane >> 5;         // which chain-pair of the four
  const int base = blockIdx.x * 4 + half * 2;   // chains base (lo), base+1 (hi)
  const int seg = blockIdx.y;
  // balanced boundaries: every wave computes exactly SEG0LEN steps
  const int t0 = (seg == 0) ? 0 : (SEG0LEN + (seg - 1) * SEGLEN); // first OUTPUT
  const int tw = (seg == 0) ? 0 : (t0 - WARM);                    // first COMPUTE
  const int tend = t0 + ((seg == 0) ? SEG0LEN : SEGLEN);

  // per-lane weights, pre-scaled; duplicated into both packed halves
  f32x2 w2[IT_ + FB_];
  #pragma unroll
  for (int q = 0; q < IT_ + FB_; ++q) w2[q] = make2(W1[q * HID_ + j] * K2LOG2E);
  const f32x2 b1v2 = make2(b1[j] * K2LOG2E);
  const float w2v = W2[j];
  const float b2v = b2[0];
  const f32x2 wfb02   = w2[IT_];
  const f32x2 mslope2 = make2(-2.0f * w2v);
  const f32x2 mbase2  = make2(w2v + b2v * (1.0f / 32.0f));
  const f32x2 k2      = make2(2.0f);
  const f32x2 km1     = make2(-1.0f);
  const f32x2 khalf   = make2(0.5f);
  const f32x2 kone    = make2(1.0f);
  const f32x2 ks1v    = make2(KS1);
  const f32x2 ks0v    = make2(KS0);

  const float* xrow0 = x + (size_t)base * T_LEN;
  const float* xrow1 = x + (size_t)(base + 1) * T_LEN;
  float* orow0 = out + (size_t)base * T_LEN;
  float* orow1 = out + (size_t)(base + 1) * T_LEN;

  // xwin[30+m] = x[tb+m] (both chains packed); xwin[0..29] = previous 30.
  // Segment start: TRUE x history (bit-exact FF path); zero-pad t<0.
  f32x2 xwin[62];
  f32x2 br[16];
  #pragma unroll
  for (int i = 0; i < 30; ++i) {
    const int idx = tw - 30 + i;
    xwin[i] = (idx >= 0) ? f32x2{xrow0[idx], xrow1[idx]} : make2(0.0f);
  }
  #pragma unroll
  for (int i = 30; i < 62; ++i) xwin[i] = make2(0.0f);
  #pragma unroll
  for (int i = 0; i < 16; ++i) br[i] = make2(0.0f);   // zero feedback (warm-up)

  // chunk of 32 upcoming x values per chain: lane j holds x[tb+j] (packed)
  f32x2 cur = {xrow0[tw + j], xrow1[tw + j]};

  for (int tb = tw; tb < tend; tb += 32) {
    // prefetch next chunk (uniform branch; clamp at the global tail)
    const int nidx = (tb + 32 < T_LEN) ? (tb + 32 + j) : (T_LEN - 1);
    f32x2 nxt = {xrow0[nidx], xrow1[nidx]};

    // hoisted broadcasts: fill xwin[30..61] (per half, per packed component)
    static_for<32>([&](auto Ic) {
      constexpr int I = Ic.value;
      f32x2 t;
      t.x = swz<(I << 5)>(cur.x);
      t.y = swz<(I << 5)>(cur.y);
      xwin[30 + I] = t;
    });

    f32x2 ystage = make2(0.0f);
    static_for<32>([&](auto Uc) {
      constexpr int U = Uc.value;   // t = tb + U

      // 31 x taps + fb taps f=1..14 — identical per-chain interleave to r4
      f32x2 a0 = b1v2, a1 = make2(0.f), a2 = make2(0.f), a3 = make2(0.f);
      static_for<IT_>([&](auto Kc) {
        constexpr int K = Kc.value;
        const f32x2 xv = xwin[30 + U - K];        // x[t-K] (compile-time idx)
        const f32x2 wv = w2[IT_ - 1 - K];         // W1[30-K][j] (scaled)
        if constexpr ((K & 3) == 0)      a0 = pk_fma(xv, wv, a0);
        else if constexpr ((K & 3) == 1) a1 = pk_fma(xv, wv, a1);
        else if constexpr ((K & 3) == 2) a2 = pk_fma(xv, wv, a2);
        else                             a3 = pk_fma(xv, wv, a3);
      });
      static_for<FB_ - 1>([&](auto Fc) {
        constexpr int F = Fc.value + 1;           // f = 1..14
        const f32x2 bv = br[(U + 31 - F) & 15];   // ytilde[t-1-F]
        const f32x2 wv = w2[IT_ + F];
        if constexpr ((F & 3) == 0)      a0 = pk_fma(bv, wv, a0);
        else if constexpr ((F & 3) == 1) a1 = pk_fma(bv, wv, a1);
        else if constexpr ((F & 3) == 2) a2 = pk_fma(bv, wv, a2);
        else                             a3 = pk_fma(bv, wv, a3);
      });
      f32x2 rest = (a0 + a1) + (a2 + a3);

      // ---- critical chain (identical values to r4..r13) ----
      f32x2 acc = pk_fma(br[(U + 15) & 15], wfb02, rest);
      f32x2 e2a;
      e2a.x = exp2_raw(acc.x);
      e2a.y = exp2_raw(acc.y);
      f32x2 ep = e2a + kone;
      f32x2 r;
      r.x = __builtin_amdgcn_rcpf(ep.x);
      r.y = __builtin_amdgcn_rcpf(ep.y);
      f32x2 yv = pk_fma(r, mslope2, mbase2);

      yv = dpp_add2<0xB1>(yv);    // quad_perm xor1
      yv = dpp_add2<0x4E>(yv);    // quad_perm xor2
      yv = dpp_add2<0x124>(yv);   // row_ror:4
      yv = dpp_add2<0x128>(yv);   // row_ror:8
      f32x2 y2;
      y2.x = cross_row16_add(yv.x);
      y2.y = cross_row16_add(yv.y);

      f32x2 h2 = y2 * khalf;
      f32x2 c2;
      c2.x = ceilf(h2.x);
      c2.y = ceilf(h2.y);
      f32x2 l2 = pk_fma(k2, c2, km1);
      f32x2 yhat;
      yhat.x = __builtin_amdgcn_fmed3f(l2.x, -3.0f, 3.0f);
      yhat.y = __builtin_amdgcn_fmed3f(l2.y, -3.0f, 3.0f);
      f32x2 d2 = yhat - y2;
      f32x2 ad;
      ad.x = fabsf(d2.x);
      ad.y = fabsf(d2.y);
      f32x2 earg = pk_fma(ks1v, ad, ks0v);
      f32x2 e2;
      e2.x = exp2_raw(earg.x);
      e2.y = exp2_raw(earg.y);
      f32x2 den = e2 + kone;
      f32x2 s2;
      s2.x = __builtin_amdgcn_rcpf(den.x);
      s2.y = __builtin_amdgcn_rcpf(den.y);
      f32x2 yt = pk_fma(s2, d2, y2);
      // ---- chain ends: yt feeds step t+1 ----

      br[U & 15] = yt;
      if (j == U) ystage = y2;
    });

    // store only inside this segment's output window (warm-up discarded)
    if (tb >= t0) {
      orow0[tb + j] = ystage.x;
      orow1[tb + j] = ystage.y;
    }
    cur = nxt;

    // slide window: keep last 30 x values for the next chunk's taps
    #pragma unroll
    for (int i = 0; i < 30; ++i) xwin[i] = xwin[i + 32];
  }
}

extern "C" void kernel_launch(void* const* d_in, const int* in_sizes, int n_in,
                              void* d_out, int out_size, void* d_ws, size_t ws_size,
                              hipStream_t stream) {
  (void)n_in; (void)out_size; (void)d_ws; (void)ws_size;
  const float* x  = (const float*)d_in[0];
  const float* W1 = (const float*)d_in[1];
  const float* b1 = (const float*)d_in[2];
  const float* W2 = (const float*)d_in[3];
  const float* b2 = (const float*)d_in[4];
  float* out = (float*)d_out;

  const int B = in_sizes[0] / T_LEN;        // 512
  const int blocks = B / 4;                 // 4 chains per 64-thread wave

  hipLaunchKernelGGL(wdrnn_eq_kernel, dim3(blocks, NSEG), dim3(64), 0, stream,
                     x, W1, b1, W2, b2, out);
}

// Round 19
// 1046.795 us; speedup vs baseline: 1.0029x; 1.0029x over previous
//
#include <hip/hip_runtime.h>
#include <type_traits>

typedef float f32x2 __attribute__((ext_vector_type(2)));

constexpr int IT_ = 31;
constexpr int FB_ = 15;
constexpr int HID_ = 32;
constexpr int T_LEN = 32768;
constexpr int NSEG = 8;            // parallel time segments per chain
constexpr int WARM = 512;          // warm-up steps (discarded) per segment
// Balanced split: every wave computes exactly SEG0LEN steps.
constexpr int SEGLEN = (T_LEN - WARM) / NSEG;   // 4032
constexpr int SEG0LEN = SEGLEN + WARM;          // 4544
// 2 * log2(e): pre-scales W1/b1 so e^{2*preact} == 2^{acc}  (same as r4..r13)
constexpr float K2LOG2E = 2.8853900817779268f;
constexpr float KS1 = 11.541560327111708f;     // 8*log2(e)
constexpr float KS0 = -5.770780163555854f;     // -4*log2(e)

static_assert(SEG0LEN % 32 == 0 && SEGLEN % 32 == 0 && WARM % 32 == 0, "chunk align");
static_assert(SEG0LEN + (NSEG - 1) * SEGLEN == T_LEN, "coverage");

template<int N, typename F>
__device__ __forceinline__ void static_for(F&& f) {
  if constexpr (N > 0) {
    static_for<N - 1>(f);
    f(std::integral_constant<int, N - 1>{});
  }
}

__device__ __forceinline__ f32x2 make2(float s) { return f32x2{s, s}; }

// packed fma: two independent scalar fmas, identical rounding to v_fma_f32.
__device__ __forceinline__ f32x2 pk_fma(f32x2 a, f32x2 b, f32x2 c) {
  return __builtin_elementwise_fma(a, b, c);
}

// per-half dpp; then one packed add. Order (v + dpp(v)) identical to r4..r13.
template<int CTRL>
__device__ __forceinline__ f32x2 dpp_add2(f32x2 v) {
  f32x2 d;
  d.x = __int_as_float(__builtin_amdgcn_update_dpp(0, __float_as_int(v.x), CTRL, 0xf, 0xf, false));
  d.y = __int_as_float(__builtin_amdgcn_update_dpp(0, __float_as_int(v.y), CTRL, 0xf, 0xf, false));
  return v + d;
}

template<int OFF>
__device__ __forceinline__ float swz(float v) {
  return __int_as_float(__builtin_amdgcn_ds_swizzle(__float_as_int(v), OFF));
}

__device__ __forceinline__ float exp2_raw(float x) {
#if __has_builtin(__builtin_amdgcn_exp2f)
  return __builtin_amdgcn_exp2f(x);
#else
  float r;
  asm("v_exp_f32 %0, %1" : "=v"(r) : "v"(x));
  return r;
#endif
}

// sum of row0+row1 within each 32-lane half, result in ALL lanes.
__device__ __forceinline__ float cross_row16_add(float v) {
#if __has_builtin(__builtin_amdgcn_permlane16_swap)
  typedef int v2i __attribute__((ext_vector_type(2)));
  v2i pr = __builtin_amdgcn_permlane16_swap(__float_as_int(v), __float_as_int(v),
                                            false, false);
  return __int_as_float(pr.x) + __int_as_float(pr.y);
#else
  float u;
  float t = v;
  asm("v_mov_b32 %0, %1\n\t"
      "v_permlane16_swap_b32 %0, %1"
      : "=&v"(u), "+v"(t));
  return u + t;
#endif
}

// r13 kernel exactly (best verified: 1155 us, absmax 0.015625), with ONE
// change: WARM 1024->512 (r16's dual-stream spilled at 256 arch VGPRs and is
// abandoned; r14/r15 stall-fill attempts regressed). Pure -9% work count in
// an issue-bound regime; per-step code byte-identical to r13.
__global__ __launch_bounds__(64)
__attribute__((amdgpu_waves_per_eu(1, 1)))
void wdrnn_eq_kernel(const float* __restrict__ x,
                     const float* __restrict__ W1,
                     const float* __restrict__ b1,
                     const float* __restrict__ W2,
                     const float* __restrict__ b2,
                     float* __restrict__ out) {
  const int lane = threadIdx.x;       // 0..63
  const int j = lane & 31;            // hidden unit index
  const int half = lane >> 5;         // which chain-pair of the four
  const int base = blockIdx.x * 4 + half * 2;   // chains base (lo), base+1 (hi)
  const int seg = blockIdx.y;
  // balanced boundaries: every wave computes exactly SEG0LEN steps
  const int t0 = (seg == 0) ? 0 : (SEG0LEN + (seg - 1) * SEGLEN); // first OUTPUT
  const int tw = (seg == 0) ? 0 : (t0 - WARM);                    // first COMPUTE
  const int tend = t0 + ((seg == 0) ? SEG0LEN : SEGLEN);

  // per-lane weights, pre-scaled; duplicated into both packed halves
  f32x2 w2[IT_ + FB_];
  #pragma unroll
  for (int q = 0; q < IT_ + FB_; ++q) w2[q] = make2(W1[q * HID_ + j] * K2LOG2E);
  const f32x2 b1v2 = make2(b1[j] * K2LOG2E);
  const float w2v = W2[j];
  const float b2v = b2[0];
  const f32x2 wfb02   = w2[IT_];
  const f32x2 mslope2 = make2(-2.0f * w2v);
  const f32x2 mbase2  = make2(w2v + b2v * (1.0f / 32.0f));
  const f32x2 k2      = make2(2.0f);
  const f32x2 km1     = make2(-1.0f);
  const f32x2 khalf   = make2(0.5f);
  const f32x2 kone    = make2(1.0f);
  const f32x2 ks1v    = make2(KS1);
  const f32x2 ks0v    = make2(KS0);

  const float* xrow0 = x + (size_t)base * T_LEN;
  const float* xrow1 = x + (size_t)(base + 1) * T_LEN;
  float* orow0 = out + (size_t)base * T_LEN;
  float* orow1 = out + (size_t)(base + 1) * T_LEN;

  // xwin[30+m] = x[tb+m] (both chains packed); xwin[0..29] = previous 30.
  // Segment start: TRUE x history (bit-exact FF path); zero-pad t<0.
  f32x2 xwin[62];
  f32x2 br[16];
  #pragma unroll
  for (int i = 0; i < 30; ++i) {
    const int idx = tw - 30 + i;
    xwin[i] = (idx >= 0) ? f32x2{xrow0[idx], xrow1[idx]} : make2(0.0f);
  }
  #pragma unroll
  for (int i = 30; i < 62; ++i) xwin[i] = make2(0.0f);
  #pragma unroll
  for (int i = 0; i < 16; ++i) br[i] = make2(0.0f);   // zero feedback (warm-up)

  // chunk of 32 upcoming x values per chain: lane j holds x[tb+j] (packed)
  f32x2 cur = {xrow0[tw + j], xrow1[tw + j]};

  for (int tb = tw; tb < tend; tb += 32) {
    // prefetch next chunk (uniform branch; clamp at the global tail)
    const int nidx = (tb + 32 < T_LEN) ? (tb + 32 + j) : (T_LEN - 1);
    f32x2 nxt = {xrow0[nidx], xrow1[nidx]};

    // hoisted broadcasts: fill xwin[30..61] (per half, per packed component)
    static_for<32>([&](auto Ic) {
      constexpr int I = Ic.value;
      f32x2 t;
      t.x = swz<(I << 5)>(cur.x);
      t.y = swz<(I << 5)>(cur.y);
      xwin[30 + I] = t;
    });

    f32x2 ystage = make2(0.0f);
    static_for<32>([&](auto Uc) {
      constexpr int U = Uc.value;   // t = tb + U

      // 31 x taps + fb taps f=1..14 — identical per-chain interleave to r4
      f32x2 a0 = b1v2, a1 = make2(0.f), a2 = make2(0.f), a3 = make2(0.f);
      static_for<IT_>([&](auto Kc) {
        constexpr int K = Kc.value;
        const f32x2 xv = xwin[30 + U - K];        // x[t-K] (compile-time idx)
        const f32x2 wv = w2[IT_ - 1 - K];         // W1[30-K][j] (scaled)
        if constexpr ((K & 3) == 0)      a0 = pk_fma(xv, wv, a0);
        else if constexpr ((K & 3) == 1) a1 = pk_fma(xv, wv, a1);
        else if constexpr ((K & 3) == 2) a2 = pk_fma(xv, wv, a2);
        else                             a3 = pk_fma(xv, wv, a3);
      });
      static_for<FB_ - 1>([&](auto Fc) {
        constexpr int F = Fc.value + 1;           // f = 1..14
        const f32x2 bv = br[(U + 31 - F) & 15];   // ytilde[t-1-F]
        const f32x2 wv = w2[IT_ + F];
        if constexpr ((F & 3) == 0)      a0 = pk_fma(bv, wv, a0);
        else if constexpr ((F & 3) == 1) a1 = pk_fma(bv, wv, a1);
        else if constexpr ((F & 3) == 2) a2 = pk_fma(bv, wv, a2);
        else                             a3 = pk_fma(bv, wv, a3);
      });
      f32x2 rest = (a0 + a1) + (a2 + a3);

      // ---- critical chain (identical values to r4..r13) ----
      f32x2 acc = pk_fma(br[(U + 15) & 15], wfb02, rest);
      f32x2 e2a;
      e2a.x = exp2_raw(acc.x);
      e2a.y = exp2_raw(acc.y);
      f32x2 ep = e2a + kone;
      f32x2 r;
      r.x = __builtin_amdgcn_rcpf(ep.x);
      r.y = __builtin_amdgcn_rcpf(ep.y);
      f32x2 yv = pk_fma(r, mslope2, mbase2);

      yv = dpp_add2<0xB1>(yv);    // quad_perm xor1
      yv = dpp_add2<0x4E>(yv);    // quad_perm xor2
      yv = dpp_add2<0x124>(yv);   // row_ror:4
      yv = dpp_add2<0x128>(yv);   // row_ror:8
      f32x2 y2;
      y2.x = cross_row16_add(yv.x);
      y2.y = cross_row16_add(yv.y);

      f32x2 h2 = y2 * khalf;
      f32x2 c2;
      c2.x = ceilf(h2.x);
      c2.y = ceilf(h2.y);
      f32x2 l2 = pk_fma(k2, c2, km1);
      f32x2 yhat;
      yhat.x = __builtin_amdgcn_fmed3f(l2.x, -3.0f, 3.0f);
      yhat.y = __builtin_amdgcn_fmed3f(l2.y, -3.0f, 3.0f);
      f32x2 d2 = yhat - y2;
      f32x2 ad;
      ad.x = fabsf(d2.x);
      ad.y = fabsf(d2.y);
      f32x2 earg = pk_fma(ks1v, ad, ks0v);
      f32x2 e2;
      e2.x = exp2_raw(earg.x);
      e2.y = exp2_raw(earg.y);
      f32x2 den = e2 + kone;
      f32x2 s2;
      s2.x = __builtin_amdgcn_rcpf(den.x);
      s2.y = __builtin_amdgcn_rcpf(den.y);
      f32x2 yt = pk_fma(s2, d2, y2);
      // ---- chain ends: yt feeds step t+1 ----

      br[U & 15] = yt;
      if (j == U) ystage = y2;
    });

    // store only inside this segment's output window (warm-up discarded)
    if (tb >= t0) {
      orow0[tb + j] = ystage.x;
      orow1[tb + j] = ystage.y;
    }
    cur = nxt;

    // slide window: keep last 30 x values for the next chunk's taps
    #pragma unroll
    for (int i = 0; i < 30; ++i) xwin[i] = xwin[i + 32];
  }
}

extern "C" void kernel_launch(void* const* d_in, const int* in_sizes, int n_in,
                              void* d_out, int out_size, void* d_ws, size_t ws_size,
                              hipStream_t stream) {
  (void)n_in; (void)out_size; (void)d_ws; (void)ws_size;
  const float* x  = (const float*)d_in[0];
  const float* W1 = (const float*)d_in[1];
  const float* b1 = (const float*)d_in[2];
  const float* W2 = (const float*)d_in[3];
  const float* b2 = (const float*)d_in[4];
  float* out = (float*)d_out;

  const int B = in_sizes[0] / T_LEN;        // 512
  const int blocks = B / 4;                 // 4 chains per 64-thread wave

  hipLaunchKernelGGL(wdrnn_eq_kernel, dim3(blocks, NSEG), dim3(64), 0, stream,
                     x, W1, b1, W2, b2, out);
}

// Round 20
// 1000.475 us; speedup vs baseline: 1.0493x; 1.0463x over previous
//
#include <hip/hip_runtime.h>
#include <type_traits>

typedef float f32x2 __attribute__((ext_vector_type(2)));

constexpr int IT_ = 31;
constexpr int FB_ = 15;
constexpr int HID_ = 32;
constexpr int T_LEN = 32768;
constexpr int NSEG = 8;            // parallel time segments per chain
constexpr int WARM = 256;          // warm-up steps (discarded) per segment
// Balanced split: every wave computes exactly SEG0LEN steps.
constexpr int SEGLEN = (T_LEN - WARM) / NSEG;   // 4064
constexpr int SEG0LEN = SEGLEN + WARM;          // 4320
// 2 * log2(e): pre-scales W1/b1 so e^{2*preact} == 2^{acc}  (same as r4..r19)
constexpr float K2LOG2E = 2.8853900817779268f;
constexpr float KS1 = 11.541560327111708f;     // 8*log2(e)
constexpr float KS0 = -5.770780163555854f;     // -4*log2(e)

static_assert(SEG0LEN % 32 == 0 && SEGLEN % 32 == 0 && WARM % 32 == 0, "chunk align");
static_assert(SEG0LEN + (NSEG - 1) * SEGLEN == T_LEN, "coverage");

template<int N, typename F>
__device__ __forceinline__ void static_for(F&& f) {
  if constexpr (N > 0) {
    static_for<N - 1>(f);
    f(std::integral_constant<int, N - 1>{});
  }
}

__device__ __forceinline__ f32x2 make2(float s) { return f32x2{s, s}; }

// packed fma: two independent scalar fmas, identical rounding to v_fma_f32.
__device__ __forceinline__ f32x2 pk_fma(f32x2 a, f32x2 b, f32x2 c) {
  return __builtin_elementwise_fma(a, b, c);
}

// per-half dpp; then one packed add. Order (v + dpp(v)) identical to r4..r19.
template<int CTRL>
__device__ __forceinline__ f32x2 dpp_add2(f32x2 v) {
  f32x2 d;
  d.x = __int_as_float(__builtin_amdgcn_update_dpp(0, __float_as_int(v.x), CTRL, 0xf, 0xf, false));
  d.y = __int_as_float(__builtin_amdgcn_update_dpp(0, __float_as_int(v.y), CTRL, 0xf, 0xf, false));
  return v + d;
}

template<int OFF>
__device__ __forceinline__ float swz(float v) {
  return __int_as_float(__builtin_amdgcn_ds_swizzle(__float_as_int(v), OFF));
}

__device__ __forceinline__ float exp2_raw(float x) {
#if __has_builtin(__builtin_amdgcn_exp2f)
  return __builtin_amdgcn_exp2f(x);
#else
  float r;
  asm("v_exp_f32 %0, %1" : "=v"(r) : "v"(x));
  return r;
#endif
}

// sum of row0+row1 within each 32-lane half, result in ALL lanes.
__device__ __forceinline__ float cross_row16_add(float v) {
#if __has_builtin(__builtin_amdgcn_permlane16_swap)
  typedef int v2i __attribute__((ext_vector_type(2)));
  v2i pr = __builtin_amdgcn_permlane16_swap(__float_as_int(v), __float_as_int(v),
                                            false, false);
  return __int_as_float(pr.x) + __int_as_float(pr.y);
#else
  float u;
  float t = v;
  asm("v_mov_b32 %0, %1\n\t"
      "v_permlane16_swap_b32 %0, %1"
      : "=&v"(u), "+v"(t));
  return u + t;
#endif
}

// r13/r19 kernel exactly (r19: 1047 us, absmax 0.0078 — all segments merged
// bit-exactly within 512 warm steps). ONE change: WARM 512->256, a pure -4.9%
// work count in the issue-bound regime. Per-step code byte-identical.
__global__ __launch_bounds__(64)
__attribute__((amdgpu_waves_per_eu(1, 1)))
void wdrnn_eq_kernel(const float* __restrict__ x,
                     const float* __restrict__ W1,
                     const float* __restrict__ b1,
                     const float* __restrict__ W2,
                     const float* __restrict__ b2,
                     float* __restrict__ out) {
  const int lane = threadIdx.x;       // 0..63
  const int j = lane & 31;            // hidden unit index
  const int half = lane >> 5;         // which chain-pair of the four
  const int base = blockIdx.x * 4 + half * 2;   // chains base (lo), base+1 (hi)
  const int seg = blockIdx.y;
  // balanced boundaries: every wave computes exactly SEG0LEN steps
  const int t0 = (seg == 0) ? 0 : (SEG0LEN + (seg - 1) * SEGLEN); // first OUTPUT
  const int tw = (seg == 0) ? 0 : (t0 - WARM);                    // first COMPUTE
  const int tend = t0 + ((seg == 0) ? SEG0LEN : SEGLEN);

  // per-lane weights, pre-scaled; duplicated into both packed halves
  f32x2 w2[IT_ + FB_];
  #pragma unroll
  for (int q = 0; q < IT_ + FB_; ++q) w2[q] = make2(W1[q * HID_ + j] * K2LOG2E);
  const f32x2 b1v2 = make2(b1[j] * K2LOG2E);
  const float w2v = W2[j];
  const float b2v = b2[0];
  const f32x2 wfb02   = w2[IT_];
  const f32x2 mslope2 = make2(-2.0f * w2v);
  const f32x2 mbase2  = make2(w2v + b2v * (1.0f / 32.0f));
  const f32x2 k2      = make2(2.0f);
  const f32x2 km1     = make2(-1.0f);
  const f32x2 khalf   = make2(0.5f);
  const f32x2 kone    = make2(1.0f);
  const f32x2 ks1v    = make2(KS1);
  const f32x2 ks0v    = make2(KS0);

  const float* xrow0 = x + (size_t)base * T_LEN;
  const float* xrow1 = x + (size_t)(base + 1) * T_LEN;
  float* orow0 = out + (size_t)base * T_LEN;
  float* orow1 = out + (size_t)(base + 1) * T_LEN;

  // xwin[30+m] = x[tb+m] (both chains packed); xwin[0..29] = previous 30.
  // Segment start: TRUE x history (bit-exact FF path); zero-pad t<0.
  f32x2 xwin[62];
  f32x2 br[16];
  #pragma unroll
  for (int i = 0; i < 30; ++i) {
    const int idx = tw - 30 + i;
    xwin[i] = (idx >= 0) ? f32x2{xrow0[idx], xrow1[idx]} : make2(0.0f);
  }
  #pragma unroll
  for (int i = 30; i < 62; ++i) xwin[i] = make2(0.0f);
  #pragma unroll
  for (int i = 0; i < 16; ++i) br[i] = make2(0.0f);   // zero feedback (warm-up)

  // chunk of 32 upcoming x values per chain: lane j holds x[tb+j] (packed)
  f32x2 cur = {xrow0[tw + j], xrow1[tw + j]};

  for (int tb = tw; tb < tend; tb += 32) {
    // prefetch next chunk (uniform branch; clamp at the global tail)
    const int nidx = (tb + 32 < T_LEN) ? (tb + 32 + j) : (T_LEN - 1);
    f32x2 nxt = {xrow0[nidx], xrow1[nidx]};

    // hoisted broadcasts: fill xwin[30..61] (per half, per packed component)
    static_for<32>([&](auto Ic) {
      constexpr int I = Ic.value;
      f32x2 t;
      t.x = swz<(I << 5)>(cur.x);
      t.y = swz<(I << 5)>(cur.y);
      xwin[30 + I] = t;
    });

    f32x2 ystage = make2(0.0f);
    static_for<32>([&](auto Uc) {
      constexpr int U = Uc.value;   // t = tb + U

      // 31 x taps + fb taps f=1..14 — identical per-chain interleave to r4
      f32x2 a0 = b1v2, a1 = make2(0.f), a2 = make2(0.f), a3 = make2(0.f);
      static_for<IT_>([&](auto Kc) {
        constexpr int K = Kc.value;
        const f32x2 xv = xwin[30 + U - K];        // x[t-K] (compile-time idx)
        const f32x2 wv = w2[IT_ - 1 - K];         // W1[30-K][j] (scaled)
        if constexpr ((K & 3) == 0)      a0 = pk_fma(xv, wv, a0);
        else if constexpr ((K & 3) == 1) a1 = pk_fma(xv, wv, a1);
        else if constexpr ((K & 3) == 2) a2 = pk_fma(xv, wv, a2);
        else                             a3 = pk_fma(xv, wv, a3);
      });
      static_for<FB_ - 1>([&](auto Fc) {
        constexpr int F = Fc.value + 1;           // f = 1..14
        const f32x2 bv = br[(U + 31 - F) & 15];   // ytilde[t-1-F]
        const f32x2 wv = w2[IT_ + F];
        if constexpr ((F & 3) == 0)      a0 = pk_fma(bv, wv, a0);
        else if constexpr ((F & 3) == 1) a1 = pk_fma(bv, wv, a1);
        else if constexpr ((F & 3) == 2) a2 = pk_fma(bv, wv, a2);
        else                             a3 = pk_fma(bv, wv, a3);
      });
      f32x2 rest = (a0 + a1) + (a2 + a3);

      // ---- critical chain (identical values to r4..r19) ----
      f32x2 acc = pk_fma(br[(U + 15) & 15], wfb02, rest);
      f32x2 e2a;
      e2a.x = exp2_raw(acc.x);
      e2a.y = exp2_raw(acc.y);
      f32x2 ep = e2a + kone;
      f32x2 r;
      r.x = __builtin_amdgcn_rcpf(ep.x);
      r.y = __builtin_amdgcn_rcpf(ep.y);
      f32x2 yv = pk_fma(r, mslope2, mbase2);

      yv = dpp_add2<0xB1>(yv);    // quad_perm xor1
      yv = dpp_add2<0x4E>(yv);    // quad_perm xor2
      yv = dpp_add2<0x124>(yv);   // row_ror:4
      yv = dpp_add2<0x128>(yv);   // row_ror:8
      f32x2 y2;
      y2.x = cross_row16_add(yv.x);
      y2.y = cross_row16_add(yv.y);

      f32x2 h2 = y2 * khalf;
      f32x2 c2;
      c2.x = ceilf(h2.x);
      c2.y = ceilf(h2.y);
      f32x2 l2 = pk_fma(k2, c2, km1);
      f32x2 yhat;
      yhat.x = __builtin_amdgcn_fmed3f(l2.x, -3.0f, 3.0f);
      yhat.y = __builtin_amdgcn_fmed3f(l2.y, -3.0f, 3.0f);
      f32x2 d2 = yhat - y2;
      f32x2 ad;
      ad.x = fabsf(d2.x);
      ad.y = fabsf(d2.y);
      f32x2 earg = pk_fma(ks1v, ad, ks0v);
      f32x2 e2;
      e2.x = exp2_raw(earg.x);
      e2.y = exp2_raw(earg.y);
      f32x2 den = e2 + kone;
      f32x2 s2;
      s2.x = __builtin_amdgcn_rcpf(den.x);
      s2.y = __builtin_amdgcn_rcpf(den.y);
      f32x2 yt = pk_fma(s2, d2, y2);
      // ---- chain ends: yt feeds step t+1 ----

      br[U & 15] = yt;
      if (j == U) ystage = y2;
    });

    // store only inside this segment's output window (warm-up discarded)
    if (tb >= t0) {
      orow0[tb + j] = ystage.x;
      orow1[tb + j] = ystage.y;
    }
    cur = nxt;

    // slide window: keep last 30 x values for the next chunk's taps
    #pragma unroll
    for (int i = 0; i < 30; ++i) xwin[i] = xwin[i + 32];
  }
}

extern "C" void kernel_launch(void* const* d_in, const int* in_sizes, int n_in,
                              void* d_out, int out_size, void* d_ws, size_t ws_size,
                              hipStream_t stream) {
  (void)n_in; (void)out_size; (void)d_ws; (void)ws_size;
  const float* x  = (const float*)d_in[0];
  const float* W1 = (const float*)d_in[1];
  const float* b1 = (const float*)d_in[2];
  const float* W2 = (const float*)d_in[3];
  const float* b2 = (const float*)d_in[4];
  float* out = (float*)d_out;

  const int B = in_sizes[0] / T_LEN;        // 512
  const int blocks = B / 4;                 // 4 chains per 64-thread wave

  hipLaunchKernelGGL(wdrnn_eq_kernel, dim3(blocks, NSEG), dim3(64), 0, stream,
                     x, W1, b1, W2, b2, out);
}